// Round 9
// baseline (481.667 us; speedup 1.0000x reference)
//
#include <hip/hip_runtime.h>
#include <hip/hip_bf16.h>
#include <stdint.h>

// Problem constants (from reference setup_inputs)
#define JT 5           // edge types
#define NE 150000      // edges per type
#define NC 2           // channels
#define NDIM 4096      // nodes
#define KDIM 4096
#define NNZ (JT * NE)  // 750000 raw edges (duplicates fine: linearity == coalesce)
constexpr size_t MAT = (size_t)NDIM * NDIM;   // 16,777,216
constexpr size_t HN  = (size_t)NC * MAT;      // 33,554,432 (H element count)

typedef __bf16 bf16x8 __attribute__((ext_vector_type(8)));
typedef float  f32x4  __attribute__((ext_vector_type(4)));

// ---------------------------------------------------------------- softmax
__global__ void softmax_k(const float* __restrict__ w1, const float* __restrict__ w2,
                          float* __restrict__ fbuf, float* __restrict__ out_tail) {
    int t = threadIdx.x;
    if (t < 2 * NC) {
        const float* w = (t < NC) ? w1 : w2;
        int c = t % NC;
        float v[JT];
        float mx = -1e30f;
        for (int j = 0; j < JT; ++j) { v[j] = w[c * JT + j]; mx = fmaxf(mx, v[j]); }
        float s = 0.f;
        for (int j = 0; j < JT; ++j) { v[j] = expf(v[j] - mx); s += v[j]; }
        float inv = 1.0f / s;
        for (int j = 0; j < JT; ++j) {
            float f = v[j] * inv;
            fbuf[t * JT + j] = f;       // rows: f1c0, f1c1, f2c0, f2c1
            out_tail[t * JT + j] = f;   // flat (f1, f2) output order
        }
    }
}

// ---------------------------------------------------------------- scatter
// 4-channel interleaved cell matrix Xi[r][c] = {f1c0*v, f1c1*v, f2c0*v, f2c1*v}
// (4 x bf16 = 8 B). Both pk-atomics of an edge hit the SAME 64B line.
__device__ __forceinline__ void pkadd2(__bf16* p, float lo, float hi) {
    uint16_t a = __builtin_bit_cast(uint16_t, (__bf16)lo);
    uint16_t b = __builtin_bit_cast(uint16_t, (__bf16)hi);
    uint32_t pk = ((uint32_t)b << 16) | a;   // lo -> [addr], hi -> [addr+2]
    asm volatile("global_atomic_pk_add_bf16 %0, %1, off"
                 :: "v"((uint64_t)(uintptr_t)p), "v"(pk) : "memory");
}

__global__ void scatter2_k(const int* __restrict__ ei, const float* __restrict__ ev,
                           const float* __restrict__ fbuf, __bf16* __restrict__ Xi) {
    int idx = blockIdx.x * blockDim.x + threadIdx.x;
    if (idx >= NNZ) return;
    int j = idx / NE;
    int e = idx - j * NE;
    int r = ei[(size_t)j * 2 * NE + e];
    int c = ei[(size_t)j * 2 * NE + NE + e];
    float v = ev[idx];
    size_t cell = ((size_t)r * NDIM + c) * 4;       // 4 bf16 per cell, 8B-aligned
    pkadd2(Xi + cell,     fbuf[j]          * v, fbuf[JT + j]     * v);  // f1 ch0,ch1
    pkadd2(Xi + cell + 2, fbuf[2 * JT + j] * v, fbuf[3 * JT + j] * v);  // f2 ch0,ch1
}

// ---------------------------------------------------------------- repack
// 64x64 cell tile per block: deinterleave Xi into A1[ch][r][c] (row-major)
// and A2T[ch][c][r] (transposed via LDS). Pure-BW pass.
__device__ __forceinline__ uint4 gather8(const ushort (*s)[65], int rr, int e8) {
    uint4 v;
    v.x = (uint32_t)s[rr][e8 + 0] | ((uint32_t)s[rr][e8 + 1] << 16);
    v.y = (uint32_t)s[rr][e8 + 2] | ((uint32_t)s[rr][e8 + 3] << 16);
    v.z = (uint32_t)s[rr][e8 + 4] | ((uint32_t)s[rr][e8 + 5] << 16);
    v.w = (uint32_t)s[rr][e8 + 6] | ((uint32_t)s[rr][e8 + 7] << 16);
    return v;
}

__global__ __launch_bounds__(256) void repack_k(const ushort4* __restrict__ Xi,
                                                __bf16* __restrict__ A1,
                                                __bf16* __restrict__ A2T) {
    __shared__ ushort s10[64][65];   // f1 ch0, [row][col]
    __shared__ ushort s11[64][65];   // f1 ch1, [row][col]
    __shared__ ushort s20[64][65];   // f2 ch0, [col][row]  (pre-transposed)
    __shared__ ushort s21[64][65];   // f2 ch1, [col][row]
    const int r0 = blockIdx.y * 64, c0 = blockIdx.x * 64;
    const int t = threadIdx.x;

#pragma unroll
    for (int it = 0; it < 16; ++it) {
        int li = t + 256 * it;              // 0..4095
        int rr = li >> 6, cc = li & 63;
        ushort4 v = Xi[(size_t)(r0 + rr) * NDIM + (c0 + cc)];
        s10[rr][cc] = v.x; s11[rr][cc] = v.y;
        s20[cc][rr] = v.z; s21[cc][rr] = v.w;
    }
    __syncthreads();

#pragma unroll
    for (int a = 0; a < 2; ++a) {
        int w = t + 256 * a;                // 0..511
        int rr = w >> 3, e8 = (w & 7) << 3; // row-in-tile, 8-elem chunk
        *(uint4*)(A1 +        (size_t)(r0 + rr) * NDIM + c0 + e8) = gather8(s10, rr, e8);
        *(uint4*)(A1 + MAT +  (size_t)(r0 + rr) * NDIM + c0 + e8) = gather8(s11, rr, e8);
        *(uint4*)(A2T +       (size_t)(c0 + rr) * NDIM + r0 + e8) = gather8(s20, rr, e8);
        *(uint4*)(A2T + MAT + (size_t)(c0 + rr) * NDIM + r0 + e8) = gather8(s21, rr, e8);
    }
}

// ---------------------------------------------------------------- GEMM
// 256x256, BK=64, 8 waves (2M x 4N). Round-9 change: B operand bypasses LDS
// (per-wave register loads straight from global; B^T fragment reads are
// 64B-line-efficient). LDS holds A only (64 KiB dbuf). Cycle model: LDS/tile
// = 128KB read + 32KB write = 625 cyc @256B/cyc ~= MFMA 620 cyc (was 1125).
// Schedule per tile: P0(A0,B0) P1(A0,B1) P2(A1,B1) P3(A1,B0); prefetch for
// t+1 at P0 (stage A0 + b0 regs), P1 (b1 regs), P2 (stage A1). Gates
// vmcnt(6)/(8)/(10) (never 0; 6-12 loads in flight); barriers only at P0/P2
// (cross-wave A hazards); B regs wave-private. B dbuf by tile parity with
// static names (bE/bO), loop unrolled x2, last tile peeled (gates 6/2/0).
// Hazard ledger: stage A_h(t+1) overwrites A_h(t-1) whose readers drained
// per-wave (lgkm0) before >=1 intervening barrier; A_h(t) reads gated by
// vmcnt + barrier; b(t+1) writes target the parity set last read at t-1
// (same-wave program order).
#define BM 256
#define BN 256
#define BK 64
#define NT (KDIM / BK)

__device__ __forceinline__ void gl_lds16(const __bf16* g, __bf16* l) {
    __builtin_amdgcn_global_load_lds(
        (const __attribute__((address_space(1))) void*)(uintptr_t)g,
        (__attribute__((address_space(3))) void*)l, 16, 0, 0);
}

#define GATE_(N) asm volatile("s_waitcnt vmcnt(" #N ")" ::: "memory")
#define GATE(N) GATE_(N)
#define FENCE asm volatile("" ::: "memory")

#define STAGEA(H, TT) do {                                                        \
    _Pragma("unroll")                                                             \
    for (int unit = 0; unit < 2; ++unit) {                                        \
        const __bf16* src = Ab + (size_t)((H) * 128 + unit * 64) * KDIM           \
                               + (size_t)(TT) * BK;                               \
        __bf16* dst = (__bf16*)(smb + ((TT) & 1) * 32768 + (H) * 16384            \
                                + unit * 8192 + wv * 1024);                       \
        gl_lds16(src, dst);                                                       \
    }                                                                             \
} while (0)

#define LOADB(DST, BH, TT) do {                                                   \
    _Pragma("unroll")                                                             \
    for (int n = 0; n < 2; ++n)                                                   \
        _Pragma("unroll")                                                         \
        for (int ks = 0; ks < 2; ++ks)                                            \
            DST[BH][n][ks] = *(const bf16x8*)(Bc +                                \
                (size_t)((BH) * 128 + n * 16) * KDIM + (size_t)(TT) * BK + ks * 32); \
} while (0)

#define READA(H) do {                                                             \
    _Pragma("unroll")                                                             \
    for (int i = 0; i < 4; ++i)                                                   \
        _Pragma("unroll")                                                         \
        for (int ks = 0; ks < 2; ++ks)                                            \
            af[i][ks] = *(const bf16x8*)(ldsA + (H) * 16384 +                     \
                ((((rAl + i * 16) * 128) + ks * 64 + kb) ^ swz));                 \
} while (0)

#define MFMA16(AH, BH, BSET) do {                                                 \
    asm volatile("s_waitcnt lgkmcnt(0)" ::: "memory");                            \
    __builtin_amdgcn_s_setprio(1);                                                \
    _Pragma("unroll")                                                             \
    for (int i = 0; i < 4; ++i)                                                   \
        _Pragma("unroll")                                                         \
        for (int n = 0; n < 2; ++n)                                               \
            _Pragma("unroll")                                                     \
            for (int ks = 0; ks < 2; ++ks)                                        \
                acc[AH][BH][i][n] = __builtin_amdgcn_mfma_f32_16x16x32_bf16(      \
                    af[i][ks], BSET[BH][n][ks], acc[AH][BH][i][n], 0, 0, 0);      \
    __builtin_amdgcn_s_setprio(0);                                                \
} while (0)

// One K-tile. BCUR = this tile's B regs, BNXT = next tile's. HN = has next.
#define TILE(T, BCUR, BNXT, HN, G0, G1, G2) do {                                  \
    const char* ldsA = smb + ((T) & 1) * 32768;                                   \
    GATE(G0);                                                                     \
    __builtin_amdgcn_s_barrier();                                                 \
    FENCE;                                                                        \
    if (HN) { STAGEA(0, (T) + 1); LOADB(BNXT, 0, (T) + 1); }                      \
    READA(0);                                                                     \
    MFMA16(0, 0, BCUR);                                                           \
    GATE(G1);                                                                     \
    FENCE;                                                                        \
    if (HN) { LOADB(BNXT, 1, (T) + 1); }                                          \
    MFMA16(0, 1, BCUR);                                                           \
    GATE(G2);                                                                     \
    __builtin_amdgcn_s_barrier();                                                 \
    FENCE;                                                                        \
    if (HN) { STAGEA(1, (T) + 1); }                                               \
    READA(1);                                                                     \
    MFMA16(1, 1, BCUR);                                                           \
    MFMA16(1, 0, BCUR);                                                           \
} while (0)

__global__ __launch_bounds__(512, 2) void gemm_k(const __bf16* __restrict__ A,
                                                 const __bf16* __restrict__ B,
                                                 float* __restrict__ C) {
    // A only, double-buffered: 2 x 32 KiB = 64 KiB
    __shared__ __align__(16) __bf16 sm[2 * 16384];

    const int u    = threadIdx.x;       // 0..511
    const int lane = u & 63;
    const int wv   = u >> 6;            // wave 0..7
    const int wr   = (wv >> 2) * 64;    // wave row offset within 128-row half
    const int wc   = (wv & 3) * 32;     // wave col offset within 128-col half
    const size_t matoff = (size_t)blockIdx.z * MAT;
    const size_t brow   = (size_t)blockIdx.y * BM;
    const size_t bcol   = (size_t)blockIdx.x * BN;

    // A staging geometry (pre-inverse-swizzled global source, linear LDS dest)
    const int srow = u >> 3;                       // row within 64-row unit
    const int kc   = (u & 7) ^ (srow & 7);         // inverse-swizzled k-chunk
    const __bf16* Ab = A + matoff + (brow + srow) * KDIM + kc * 8;
    char* const smb = (char*)sm;

    // B per-lane register-load base: col = bcol + wc + (lane&15), k-octet base
    const __bf16* Bc = B + matoff + (bcol + wc + (size_t)(lane & 15)) * KDIM
                         + ((lane >> 4) << 3);

    // A fragment read geometry (swizzled ds_read_b128)
    const int rAl = wr + (lane & 15);   // A row within half (+ i*16)
    const int kb  = (lane >> 4) * 16;   // byte offset of lane's k-octet
    const int swz = (lane & 7) << 4;    // XOR swizzle mask

    f32x4 acc[2][2][4][2];
#pragma unroll
    for (int a = 0; a < 2; ++a)
#pragma unroll
        for (int b = 0; b < 2; ++b)
#pragma unroll
            for (int i = 0; i < 4; ++i)
#pragma unroll
                for (int n = 0; n < 2; ++n) acc[a][b][i][n] = (f32x4){0.f, 0.f, 0.f, 0.f};

    bf16x8 af[4][2];
    bf16x8 bE[2][2][2], bO[2][2][2];    // B frag dbuf by tile parity

    // prologue: tile 0 in issue order [A0 stage, b0, b1, A1 stage]
    STAGEA(0, 0);
    LOADB(bE, 0, 0);
    LOADB(bE, 1, 0);
    STAGEA(1, 0);

    // tiles 0..61 (unrolled x2 for static B parity naming)
    for (int t = 0; t < NT - 2; t += 2) {
        TILE(t,     bE, bO, true, 6, 8, 10);
        TILE(t + 1, bO, bE, true, 6, 8, 10);
    }
    // tile 62: prefetches tile 63; tile 63: peeled, tightening gates
    TILE(NT - 2, bE, bO, true,  6, 8, 10);
    TILE(NT - 1, bO, bE, false, 6, 2, 0);

    // epilogue: C/D layout col = lane&15, row = (lane>>4)*4 + reg
    float* Cc = C + matoff;
#pragma unroll
    for (int a = 0; a < 2; ++a)
#pragma unroll
        for (int b = 0; b < 2; ++b)
#pragma unroll
            for (int i = 0; i < 4; ++i) {
                int orow0 = (int)brow + a * 128 + wr + i * 16 + (lane >> 4) * 4;
#pragma unroll
                for (int n = 0; n < 2; ++n) {
                    int ocol = (int)bcol + b * 128 + wc + n * 16 + (lane & 15);
                    float* p = Cc + (size_t)orow0 * NDIM + ocol;
#pragma unroll
                    for (int jj = 0; jj < 4; ++jj) p[(size_t)jj * NDIM] = acc[a][b][i][n][jj];
                }
            }
}

// ---------------------------------------------------------------- launch
extern "C" void kernel_launch(void* const* d_in, const int* in_sizes, int n_in,
                              void* d_out, int out_size, void* d_ws, size_t ws_size,
                              hipStream_t stream) {
    const int*   ei = (const int*)d_in[0];
    const float* ev = (const float*)d_in[1];
    const float* w1 = (const float*)d_in[2];
    const float* w2 = (const float*)d_in[3];
    float* out = (float*)d_out;

    // ws: A1 bf16 (67MB, 2ch) | A2T bf16 (67MB, 2ch) | fbuf (20 floats)
    char* ws = (char*)d_ws;
    __bf16* A1b  = (__bf16*)ws;
    __bf16* A2b  = (__bf16*)(ws + HN * sizeof(__bf16));
    float*  fbuf = (float*)(ws + 2 * HN * sizeof(__bf16));
    size_t needed = 2 * HN * sizeof(__bf16) + 32 * sizeof(float);
    if (ws_size < needed) return;

    // Xi (4-ch interleaved cell matrix, 134 MB) lives in the dead H region of
    // d_out; the GEMM overwrites it last.
    __bf16* Xi = (__bf16*)d_out;

    softmax_k<<<dim3(1), dim3(64), 0, stream>>>(w1, w2, fbuf, out + HN);

    hipMemsetAsync(Xi, 0, HN * sizeof(float), stream);

    const int nb = (NNZ + 255) / 256;
    scatter2_k<<<dim3(nb), dim3(256), 0, stream>>>(ei, ev, fbuf, Xi);

    repack_k<<<dim3(64, 64), dim3(256), 0, stream>>>((const ushort4*)Xi, A1b, A2b);

    gemm_k<<<dim3(NDIM / BN, NDIM / BM, NC), dim3(512), 0, stream>>>(A1b, A2b, out);
}

// Round 10
// 330.886 us; speedup vs baseline: 1.4557x; 1.4557x over previous
//
#include <hip/hip_runtime.h>
#include <hip/hip_bf16.h>
#include <stdint.h>

// Problem constants (from reference setup_inputs)
#define JT 5           // edge types
#define NE 150000      // edges per type
#define NC 2           // channels
#define NDIM 4096      // nodes
#define KDIM 4096
#define NNZ (JT * NE)  // 750000 raw edges (duplicates fine: linearity == coalesce)
constexpr size_t MAT = (size_t)NDIM * NDIM;   // 16,777,216
constexpr size_t HN  = (size_t)NC * MAT;      // 33,554,432 (H element count)

typedef __bf16 bf16x8 __attribute__((ext_vector_type(8)));
typedef float  f32x4  __attribute__((ext_vector_type(4)));

// ---------------------------------------------------------------- softmax
__global__ void softmax_k(const float* __restrict__ w1, const float* __restrict__ w2,
                          float* __restrict__ fbuf, float* __restrict__ out_tail) {
    int t = threadIdx.x;
    if (t < 2 * NC) {
        const float* w = (t < NC) ? w1 : w2;
        int c = t % NC;
        float v[JT];
        float mx = -1e30f;
        for (int j = 0; j < JT; ++j) { v[j] = w[c * JT + j]; mx = fmaxf(mx, v[j]); }
        float s = 0.f;
        for (int j = 0; j < JT; ++j) { v[j] = expf(v[j] - mx); s += v[j]; }
        float inv = 1.0f / s;
        for (int j = 0; j < JT; ++j) {
            float f = v[j] * inv;
            fbuf[t * JT + j] = f;       // rows: f1c0, f1c1, f2c0, f2c1
            out_tail[t * JT + j] = f;   // flat (f1, f2) output order
        }
    }
}

// ---------------------------------------------------------------- scatter
// 4-channel interleaved cell matrix Xi[r][c] = {f1c0*v, f1c1*v, f2c0*v, f2c1*v}
// (4 x bf16 = 8 B). Both pk-atomics of an edge hit the SAME 64B line.
__device__ __forceinline__ void pkadd2(__bf16* p, float lo, float hi) {
    uint16_t a = __builtin_bit_cast(uint16_t, (__bf16)lo);
    uint16_t b = __builtin_bit_cast(uint16_t, (__bf16)hi);
    uint32_t pk = ((uint32_t)b << 16) | a;   // lo -> [addr], hi -> [addr+2]
    asm volatile("global_atomic_pk_add_bf16 %0, %1, off"
                 :: "v"((uint64_t)(uintptr_t)p), "v"(pk) : "memory");
}

__global__ void scatter2_k(const int* __restrict__ ei, const float* __restrict__ ev,
                           const float* __restrict__ fbuf, __bf16* __restrict__ Xi) {
    int idx = blockIdx.x * blockDim.x + threadIdx.x;
    if (idx >= NNZ) return;
    int j = idx / NE;
    int e = idx - j * NE;
    int r = ei[(size_t)j * 2 * NE + e];
    int c = ei[(size_t)j * 2 * NE + NE + e];
    float v = ev[idx];
    size_t cell = ((size_t)r * NDIM + c) * 4;       // 4 bf16 per cell, 8B-aligned
    pkadd2(Xi + cell,     fbuf[j]          * v, fbuf[JT + j]     * v);  // f1 ch0,ch1
    pkadd2(Xi + cell + 2, fbuf[2 * JT + j] * v, fbuf[3 * JT + j] * v);  // f2 ch0,ch1
}

// ---------------------------------------------------------------- repack
// 64x64 cell tile per block: deinterleave Xi into A1[ch][r][c] (row-major)
// and A2T[ch][c][r] (transposed via LDS). Pure-BW pass.
__device__ __forceinline__ uint4 gather8(const ushort (*s)[65], int rr, int e8) {
    uint4 v;
    v.x = (uint32_t)s[rr][e8 + 0] | ((uint32_t)s[rr][e8 + 1] << 16);
    v.y = (uint32_t)s[rr][e8 + 2] | ((uint32_t)s[rr][e8 + 3] << 16);
    v.z = (uint32_t)s[rr][e8 + 4] | ((uint32_t)s[rr][e8 + 5] << 16);
    v.w = (uint32_t)s[rr][e8 + 6] | ((uint32_t)s[rr][e8 + 7] << 16);
    return v;
}

__global__ __launch_bounds__(256) void repack_k(const ushort4* __restrict__ Xi,
                                                __bf16* __restrict__ A1,
                                                __bf16* __restrict__ A2T) {
    __shared__ ushort s10[64][65];   // f1 ch0, [row][col]
    __shared__ ushort s11[64][65];   // f1 ch1, [row][col]
    __shared__ ushort s20[64][65];   // f2 ch0, [col][row]  (pre-transposed)
    __shared__ ushort s21[64][65];   // f2 ch1, [col][row]
    const int r0 = blockIdx.y * 64, c0 = blockIdx.x * 64;
    const int t = threadIdx.x;

#pragma unroll
    for (int it = 0; it < 16; ++it) {
        int li = t + 256 * it;              // 0..4095
        int rr = li >> 6, cc = li & 63;
        ushort4 v = Xi[(size_t)(r0 + rr) * NDIM + (c0 + cc)];
        s10[rr][cc] = v.x; s11[rr][cc] = v.y;
        s20[cc][rr] = v.z; s21[cc][rr] = v.w;
    }
    __syncthreads();

#pragma unroll
    for (int a = 0; a < 2; ++a) {
        int w = t + 256 * a;                // 0..511
        int rr = w >> 3, e8 = (w & 7) << 3; // row-in-tile, 8-elem chunk
        *(uint4*)(A1 +        (size_t)(r0 + rr) * NDIM + c0 + e8) = gather8(s10, rr, e8);
        *(uint4*)(A1 + MAT +  (size_t)(r0 + rr) * NDIM + c0 + e8) = gather8(s11, rr, e8);
        *(uint4*)(A2T +       (size_t)(c0 + rr) * NDIM + r0 + e8) = gather8(s20, rr, e8);
        *(uint4*)(A2T + MAT + (size_t)(c0 + rr) * NDIM + r0 + e8) = gather8(s21, rr, e8);
    }
}

// ---------------------------------------------------------------- GEMM
// Round-8 verified structure (quadrant phases, half-tile staging, counted
// vmcnt(4) gates, barriers at P0/P1/P2, peeled last tile). Round-10 change:
// BOTH B-half fragments held in registers (bf0/bf1) so P3 re-reads NOTHING
// from LDS (was 4 ds_read_b128/wave). Per-wave LDS reads drop to the
// wave-tiling floor: 16KB A + 8KB B. Stage/gate/barrier structure and
// hazard ledger are byte-identical to round 8.
#define BM 256
#define BN 256
#define BK 64
#define NT (KDIM / BK)

__device__ __forceinline__ void gl_lds16(const __bf16* g, __bf16* l) {
    __builtin_amdgcn_global_load_lds(
        (const __attribute__((address_space(1))) void*)(uintptr_t)g,
        (__attribute__((address_space(3))) void*)l, 16, 0, 0);
}

#define READA(AH) do {                                                            \
    _Pragma("unroll")                                                             \
    for (int i = 0; i < 4; ++i)                                                   \
        _Pragma("unroll")                                                         \
        for (int ks = 0; ks < 2; ++ks)                                            \
            af[i][ks] = *(const bf16x8*)(ldsAc + (AH) * 16384 +                   \
                ((((rAl + i * 16) * 128) + ks * 64 + kb) ^ swz));                 \
} while (0)

#define READBH(DST, BH) do {                                                      \
    _Pragma("unroll")                                                             \
    for (int n = 0; n < 2; ++n)                                                   \
        _Pragma("unroll")                                                         \
        for (int ks = 0; ks < 2; ++ks)                                            \
            DST[n][ks] = *(const bf16x8*)(ldsBc + (BH) * 16384 +                  \
                ((((rBl + n * 16) * 128) + ks * 64 + kb) ^ swz));                 \
} while (0)

#define MFMA16(AH, BH, BSET) do {                                                 \
    asm volatile("s_waitcnt lgkmcnt(0)" ::: "memory");                            \
    __builtin_amdgcn_s_setprio(1);                                                \
    _Pragma("unroll")                                                             \
    for (int i = 0; i < 4; ++i)                                                   \
        _Pragma("unroll")                                                         \
        for (int n = 0; n < 2; ++n)                                               \
            _Pragma("unroll")                                                     \
            for (int ks = 0; ks < 2; ++ks)                                        \
                acc[AH][BH][i][n] = __builtin_amdgcn_mfma_f32_16x16x32_bf16(      \
                    af[i][ks], BSET[n][ks], acc[AH][BH][i][n], 0, 0, 0);          \
    __builtin_amdgcn_s_setprio(0);                                                \
} while (0)

#define GATE_BAR(N) do {                                                          \
    asm volatile("s_waitcnt vmcnt(" #N ")" ::: "memory");                         \
    __builtin_amdgcn_s_barrier();                                                 \
    asm volatile("" ::: "memory");                                                \
} while (0)

__global__ __launch_bounds__(512, 2) void gemm_k(const __bf16* __restrict__ A,
                                                 const __bf16* __restrict__ B,
                                                 float* __restrict__ C) {
    // [buf][A half0|half1 | B half0|half1], buf = 64 KiB, total 128 KiB
    __shared__ __align__(16) __bf16 sm[65536];

    const int u    = threadIdx.x;       // 0..511
    const int lane = u & 63;
    const int wv   = u >> 6;            // wave 0..7
    const int wr   = (wv >> 2) * 64;    // wave row offset within 128-row quadrant
    const int wc   = (wv & 3) * 32;     // wave col offset within 128-col quadrant
    const size_t matoff = (size_t)blockIdx.z * MAT;
    const size_t brow   = (size_t)blockIdx.y * BM;
    const size_t bcol   = (size_t)blockIdx.x * BN;

    // staging: unit = 64 rows x 64 k = one 512-thread x 16B gl_lds (8 KiB);
    // half = 2 units (128 rows). Global source pre-inverse-swizzled.
    const int srow = u >> 3;                       // row within unit, 0..63
    const int kc   = (u & 7) ^ (srow & 7);         // inverse-swizzled k-chunk
    const __bf16* Ab = A + matoff + (brow + srow) * KDIM + kc * 8;
    const __bf16* Bb = B + matoff + (bcol + srow) * KDIM + kc * 8;
    char* const smb = (char*)sm;

    auto stage = [&](int mat, int h, int tt) {
        const __bf16* base = mat ? Bb : Ab;
#pragma unroll
        for (int unit = 0; unit < 2; ++unit) {
            const __bf16* src = base + (size_t)(h * 128 + unit * 64) * KDIM + (size_t)tt * BK;
            __bf16* dst = (__bf16*)(smb + (tt & 1) * 65536 + mat * 32768 +
                                    h * 16384 + unit * 8192 + wv * 1024);
            gl_lds16(src, dst);
        }
    };

    const int rAl = wr + (lane & 15);   // A row-in-half (+ i*16)
    const int rBl = wc + (lane & 15);   // B row-in-half (+ n*16)
    const int kb  = (lane >> 4) * 16;   // byte offset of lane's k-octet
    const int swz = (lane & 7) << 4;    // XOR swizzle mask

    f32x4 acc[2][2][4][2];
#pragma unroll
    for (int a = 0; a < 2; ++a)
#pragma unroll
        for (int b = 0; b < 2; ++b)
#pragma unroll
            for (int i = 0; i < 4; ++i)
#pragma unroll
                for (int n = 0; n < 2; ++n) acc[a][b][i][n] = (f32x4){0.f, 0.f, 0.f, 0.f};

    bf16x8 af[4][2], bf0[2][2], bf1[2][2];   // both B halves live in regs

    // prologue: tile 0's halves in first-use order A0, B0, B1, A1
    stage(0, 0, 0); stage(1, 0, 0); stage(1, 1, 0); stage(0, 1, 0);

    for (int t = 0; t < NT - 1; ++t) {
        const char* ldsAc = smb + (t & 1) * 65536;
        const char* ldsBc = ldsAc + 32768;
        const int nxt = t + 1;
        // P0: quadrant (A0,B0)
        GATE_BAR(4);
        stage(0, 0, nxt);
        READA(0); READBH(bf0, 0);
        MFMA16(0, 0, bf0);
        // P1: quadrant (A0,B1) — reuse af
        GATE_BAR(4);
        stage(1, 0, nxt);
        READBH(bf1, 1);
        MFMA16(0, 1, bf1);
        // P2: quadrant (A1,B1) — reuse bf1
        GATE_BAR(4);
        stage(1, 1, nxt);
        READA(1);
        MFMA16(1, 1, bf1);
        // P3: quadrant (A1,B0) — NO LDS reads: af from P2, bf0 from P0
        stage(0, 1, nxt);
        MFMA16(1, 0, bf0);
    }
    {   // peeled last tile: no stages, tightening gates
        const char* ldsAc = smb + ((NT - 1) & 1) * 65536;
        const char* ldsBc = ldsAc + 32768;
        GATE_BAR(4);
        READA(0); READBH(bf0, 0);
        MFMA16(0, 0, bf0);
        GATE_BAR(2);
        READBH(bf1, 1);
        MFMA16(0, 1, bf1);
        GATE_BAR(0);
        READA(1);
        MFMA16(1, 1, bf1);
        MFMA16(1, 0, bf0);
    }

    // epilogue: C/D layout col = lane&15, row = (lane>>4)*4 + reg
    float* Cc = C + matoff;
#pragma unroll
    for (int a = 0; a < 2; ++a)
#pragma unroll
        for (int b = 0; b < 2; ++b)
#pragma unroll
            for (int i = 0; i < 4; ++i) {
                int orow0 = (int)brow + a * 128 + wr + i * 16 + (lane >> 4) * 4;
#pragma unroll
                for (int n = 0; n < 2; ++n) {
                    int ocol = (int)bcol + b * 128 + wc + n * 16 + (lane & 15);
                    float* p = Cc + (size_t)orow0 * NDIM + ocol;
#pragma unroll
                    for (int jj = 0; jj < 4; ++jj) p[(size_t)jj * NDIM] = acc[a][b][i][n][jj];
                }
            }
}

// ---------------------------------------------------------------- launch
extern "C" void kernel_launch(void* const* d_in, const int* in_sizes, int n_in,
                              void* d_out, int out_size, void* d_ws, size_t ws_size,
                              hipStream_t stream) {
    const int*   ei = (const int*)d_in[0];
    const float* ev = (const float*)d_in[1];
    const float* w1 = (const float*)d_in[2];
    const float* w2 = (const float*)d_in[3];
    float* out = (float*)d_out;

    // ws: A1 bf16 (67MB, 2ch) | A2T bf16 (67MB, 2ch) | fbuf (20 floats)
    char* ws = (char*)d_ws;
    __bf16* A1b  = (__bf16*)ws;
    __bf16* A2b  = (__bf16*)(ws + HN * sizeof(__bf16));
    float*  fbuf = (float*)(ws + 2 * HN * sizeof(__bf16));
    size_t needed = 2 * HN * sizeof(__bf16) + 32 * sizeof(float);
    if (ws_size < needed) return;

    // Xi (4-ch interleaved cell matrix, 134 MB) lives in the dead H region of
    // d_out; the GEMM overwrites it last.
    __bf16* Xi = (__bf16*)d_out;

    softmax_k<<<dim3(1), dim3(64), 0, stream>>>(w1, w2, fbuf, out + HN);

    hipMemsetAsync(Xi, 0, HN * sizeof(float), stream);

    const int nb = (NNZ + 255) / 256;
    scatter2_k<<<dim3(nb), dim3(256), 0, stream>>>(ei, ev, fbuf, Xi);

    repack_k<<<dim3(64, 64), dim3(256), 0, stream>>>((const ushort4*)Xi, A1b, A2b);

    gemm_k<<<dim3(NDIM / BN, NDIM / BM, NC), dim3(512), 0, stream>>>(A1b, A2b, out);
}